// Round 19
// baseline (65.398 us; speedup 1.0000x reference)
//
#include <hip/hip_runtime.h>
#include <math.h>

#define NC    64
#define NT    128
#define NS    8
#define NFEAT 16
#define NE1   4032
#define NB    1024

typedef __attribute__((ext_vector_type(8))) short short8v;   // 8 bf16 carrier
typedef __attribute__((ext_vector_type(4))) float float4v;

__device__ __forceinline__ float sigmoidf_(float x) { return 1.f / (1.f + __expf(-x)); }
__device__ __forceinline__ float tanhf_(float x) {
  const float t = __expf(2.f * x);           // saturates correctly at +-inf
  return 1.f - 2.f / (t + 1.f);
}

__device__ __forceinline__ unsigned short bf16hi(float v) {
  return (unsigned short)(__float_as_uint(v) >> 16);
}
__device__ __forceinline__ float bf16hi_f(float v) {
  return __uint_as_float(__float_as_uint(v) & 0xffff0000u);
}

// ---------------------------------------------------------------------------
// Kernel A (verified r17): block = (s, nt). Analytic M build (closed-form
// edge order e(r,c) = r*63 + c - (c>r)), rows [nt*16,+16) of P2/P3 via row
// chains, pack A-operand MFMA fragments (hi/lo bf16) for K=192 [M|P2|P3] in
// mfma_f32_16x16x32_bf16 A-layout. Afrag[s][t6(6)][nt(4)][h(2)][64][4u].
// ---------------------------------------------------------------------------
__global__ __launch_bounds__(256) void build_frags_kernel(
    const float* __restrict__ ew, unsigned int* __restrict__ Afrag) {
  const int s  = blockIdx.x & 7;
  const int nt = blockIdx.x >> 3;
  const int t  = threadIdx.x;
  const int lane = t & 63;

  __shared__ float M[64][64];       // [out-node c][in-node r]
  __shared__ float P23[2][16][64];  // local rows of P2, P3
  __shared__ float dinv[64];
  __shared__ float dpart[4][64];

  const float* w = ew + s * NE1;

  {
    const int c  = t & 63;
    const int qr = t >> 6;
    float p = 0.f;
#pragma unroll
    for (int rr = 0; rr < 16; ++rr) {
      const int r = (qr << 4) | rr;
      if (r != c) p += w[r * 63 + c - (c > r ? 1 : 0)];
    }
    dpart[qr][c] = p;
  }
  __syncthreads();
  if (t < 64) {
    const float d = dpart[0][t] + dpart[1][t] + dpart[2][t] + dpart[3][t];
    dinv[t] = (d > 0.f) ? rsqrtf(d) : 0.f;
  }
  __syncthreads();

  for (int i = t; i < 4096; i += 256) {
    const int c = i >> 6, r = i & 63;
    M[c][r] = (r == c) ? 0.f
            : dinv[r] * w[r * 63 + c - (c > r ? 1 : 0)] * dinv[c];
  }
  __syncthreads();

  {
    const int rowl = ((t >> 6) << 2) | (lane >> 4);   // 0..15
    const int i    = (nt << 4) | rowl;
    const int jg4  = (lane & 15) << 2;
    float4v a2 = {0.f, 0.f, 0.f, 0.f};
#pragma unroll 8
    for (int m = 0; m < 64; ++m) {
      const float pim = M[i][m];
      const float4v mj = *(const float4v*)(&M[m][jg4]);
      a2 += pim * mj;
    }
    *(float4v*)(&P23[0][rowl][jg4]) = a2;
    float4v a3 = {0.f, 0.f, 0.f, 0.f};
#pragma unroll 8
    for (int m = 0; m < 64; ++m) {
      const float v2m = P23[0][rowl][m];              // same-wave DS ordering
      const float4v mj = *(const float4v*)(&M[m][jg4]);
      a3 += v2m * mj;
    }
    *(float4v*)(&P23[1][rowl][jg4]) = a3;
  }
  __syncthreads();

  for (int slot = t; slot < 768; slot += 256) {
    const int t6 = slot >> 7;              // 0..5
    const int h  = (slot >> 6) & 1;
    const int lf = slot & 63;
    const int rl = lf & 15;
    const int rg = (nt << 4) | rl;
    const int kb = (t6 << 5) | ((lf >> 4) << 3);
    uint4 u;
    unsigned int uu[4];
#pragma unroll
    for (int j = 0; j < 4; ++j) {
      unsigned short us[2];
#pragma unroll
      for (int e2 = 0; e2 < 2; ++e2) {
        const int k  = kb + (j << 1) + e2;
        const int kk = k >> 6;             // 0:M, 1:P2, 2:P3
        const int m  = k & 63;
        const float v = (kk == 0) ? M[rg][m] : P23[kk - 1][rl][m];
        us[e2] = h ? bf16hi(v - bf16hi_f(v)) : bf16hi(v);
      }
      uu[j] = (unsigned int)us[0] | ((unsigned int)us[1] << 16);
    }
    u.x = uu[0]; u.y = uu[1]; u.z = uu[2]; u.w = uu[3];
    unsigned int* dst = Afrag + ((((size_t)(s * 6 + t6) * 4 + nt) * 2 + h) << 8) + (lf << 2);
    *(uint4*)dst = u;
  }
}

// ---------------------------------------------------------------------------
// Kernel B (verified r17 exact): TAGConv via MFMA (K=192, acc init = V0) +
// ReLU + max-pool. s = blk>>8, quad q = blk&255 -> XCD q%8 affinity.
// Load order: x -> Wl -> 12 A-frag b128. W via LDS uniform b128.
// NOTE r19: launched 3x (idempotent) to measure B's marginal cost via the
// total-duration delta — kernels are below the rocprof top-5 visibility
// floor set by the harness's 39us ws-poison fills.
// ---------------------------------------------------------------------------
__global__ __launch_bounds__(256) void tag_pool_mfma_kernel(
    const float* __restrict__ x, const unsigned int* __restrict__ Afrag,
    const float* __restrict__ lin_w, const float* __restrict__ lin_b,
    float* __restrict__ pooled) {
  const int t    = threadIdx.x;
  const int lane = t & 63;
  const int w    = t >> 6;
  const int s    = blockIdx.x >> 8;                // step
  const int q    = blockIdx.x & 255;               // quad -> XCD q%8
  const int g0   = q << 2;
  const int col  = lane & 15;                      // B/C column = 4*g + o

  __shared__ __align__(16) float Wl[256];                   // [ko][f]
  __shared__ __align__(16) unsigned short zT[2][3][16][72]; // [h][kk][col][m pad72]
  __shared__ __align__(16) float V0f[16][68];               // [col][m pad68]
  __shared__ float pmax[4][16];

  // x loads FIRST (stage-1 needs them before anything else)
  float xf[16];
  {
    const float* xr = x + (((size_t)(g0 + w) << 6) + lane) * NT + s * NFEAT;
#pragma unroll
    for (int i = 0; i < 4; ++i)
      *(float4*)(&xf[i << 2]) = *(const float4*)(xr + (i << 2));
  }

  // W -> LDS (1KB, one coalesced load per thread)
  Wl[t] = lin_w[t];

  // A-fragment loads (consumed after the barrier; issued behind x)
  const unsigned int* Ab = Afrag + (size_t)s * 12288 + (lane << 2);
  short8v Ah0 = *(const short8v*)(Ab + (((0 * 4 + w) * 2 + 0) << 8));
  short8v Al0 = *(const short8v*)(Ab + (((0 * 4 + w) * 2 + 1) << 8));
  short8v Ah1 = *(const short8v*)(Ab + (((1 * 4 + w) * 2 + 0) << 8));
  short8v Al1 = *(const short8v*)(Ab + (((1 * 4 + w) * 2 + 1) << 8));
  short8v Ah2 = *(const short8v*)(Ab + (((2 * 4 + w) * 2 + 0) << 8));
  short8v Al2 = *(const short8v*)(Ab + (((2 * 4 + w) * 2 + 1) << 8));
  short8v Ah3 = *(const short8v*)(Ab + (((3 * 4 + w) * 2 + 0) << 8));
  short8v Al3 = *(const short8v*)(Ab + (((3 * 4 + w) * 2 + 1) << 8));
  short8v Ah4 = *(const short8v*)(Ab + (((4 * 4 + w) * 2 + 0) << 8));
  short8v Al4 = *(const short8v*)(Ab + (((4 * 4 + w) * 2 + 1) << 8));
  short8v Ah5 = *(const short8v*)(Ab + (((5 * 4 + w) * 2 + 0) << 8));
  short8v Al5 = *(const short8v*)(Ab + (((5 * 4 + w) * 2 + 1) << 8));

  __syncthreads();   // Wl visible to all waves

  // stage 1: wave w handles graph g0+w; lane = node. W via uniform LDS b128.
#pragma unroll
  for (int ko = 0; ko < 16; ++ko) {
    const float4 w0 = *(const float4*)(&Wl[(ko << 4)]);
    const float4 w1 = *(const float4*)(&Wl[(ko << 4) + 4]);
    const float4 w2 = *(const float4*)(&Wl[(ko << 4) + 8]);
    const float4 w3 = *(const float4*)(&Wl[(ko << 4) + 12]);
    float a = 0.f;
    a = fmaf(xf[0],  w0.x, a); a = fmaf(xf[1],  w0.y, a);
    a = fmaf(xf[2],  w0.z, a); a = fmaf(xf[3],  w0.w, a);
    a = fmaf(xf[4],  w1.x, a); a = fmaf(xf[5],  w1.y, a);
    a = fmaf(xf[6],  w1.z, a); a = fmaf(xf[7],  w1.w, a);
    a = fmaf(xf[8],  w2.x, a); a = fmaf(xf[9],  w2.y, a);
    a = fmaf(xf[10], w2.z, a); a = fmaf(xf[11], w2.w, a);
    a = fmaf(xf[12], w3.x, a); a = fmaf(xf[13], w3.y, a);
    a = fmaf(xf[14], w3.z, a); a = fmaf(xf[15], w3.w, a);
    const int kk = ko >> 2;
    const int cl = (w << 2) | (ko & 3);
    if (kk == 0) {
      V0f[cl][lane] = a;
    } else {
      zT[0][kk - 1][cl][lane] = bf16hi(a);
      zT[1][kk - 1][cl][lane] = bf16hi(a - bf16hi_f(a));
    }
  }
  __syncthreads();

  // acc init = V0[col][row] (identity term)
  float4v acc = *(const float4v*)(&V0f[col][(w << 4) | ((lane >> 4) << 2)]);

  // main loop: 6 k-steps of 32 over [M|P2|P3]; wave w owns A-row-tile nt=w.
#pragma unroll
  for (int t6 = 0; t6 < 6; ++t6) {
    const short8v Ah = (t6 == 0) ? Ah0 : (t6 == 1) ? Ah1 : (t6 == 2) ? Ah2
                     : (t6 == 3) ? Ah3 : (t6 == 4) ? Ah4 : Ah5;
    const short8v Al = (t6 == 0) ? Al0 : (t6 == 1) ? Al1 : (t6 == 2) ? Al2
                     : (t6 == 3) ? Al3 : (t6 == 4) ? Al4 : Al5;
    const int kk   = t6 >> 1;                       // 0:V1, 1:V2, 2:V3
    const int mloc = ((t6 & 1) << 5) | ((lane >> 4) << 3);
    const short8v Bh = *(const short8v*)(&zT[0][kk][col][mloc]);
    const short8v Bl = *(const short8v*)(&zT[1][kk][col][mloc]);
    acc = __builtin_amdgcn_mfma_f32_16x16x32_bf16(Ah, Bh, acc, 0, 0, 0);
    acc = __builtin_amdgcn_mfma_f32_16x16x32_bf16(Al, Bh, acc, 0, 0, 0);
    acc = __builtin_amdgcn_mfma_f32_16x16x32_bf16(Ah, Bl, acc, 0, 0, 0);
  }

  // epilogue: + bias, relu, max over tile's 16 rows, then block max
  const float bsA = lin_b[0] + lin_b[4] + lin_b[8]  + lin_b[12];
  const float bsB = lin_b[1] + lin_b[5] + lin_b[9]  + lin_b[13];
  const float bsC = lin_b[2] + lin_b[6] + lin_b[10] + lin_b[14];
  const float bsD = lin_b[3] + lin_b[7] + lin_b[11] + lin_b[15];
  const int oq = col & 3;
  const float bs = (oq == 0) ? bsA : (oq == 1) ? bsB : (oq == 2) ? bsC : bsD;

  float mx = 0.f;   // relu floor: outputs >= 0
#pragma unroll
  for (int r = 0; r < 4; ++r) mx = fmaxf(mx, fmaxf(acc[r] + bs, 0.f));
  mx = fmaxf(mx, __shfl_xor(mx, 16));
  mx = fmaxf(mx, __shfl_xor(mx, 32));
  if (lane < 16) pmax[w][lane] = mx;
  __syncthreads();

  if (t < 16) {
    const float m01 = fmaxf(pmax[0][t], pmax[1][t]);
    const float m23 = fmaxf(pmax[2][t], pmax[3][t]);
    pooled[((size_t)(g0 + (t >> 2)) * NS + s) * 4 + (t & 3)] = fmaxf(m01, m23);
  }
}

// ---------------------------------------------------------------------------
// Kernel C (verified r16): LSTM + FC, one thread per graph; pooled preloaded;
// fast exp forms.
// ---------------------------------------------------------------------------
__global__ __launch_bounds__(64) void lstm_fc_kernel(
    const float* __restrict__ pooled,
    const float* __restrict__ w_ih, const float* __restrict__ b_ih,
    const float* __restrict__ w_hh, const float* __restrict__ b_hh,
    const float* __restrict__ fc_w, const float* __restrict__ fc_b,
    float* __restrict__ out) {
  const int g = blockIdx.x * blockDim.x + threadIdx.x;
  if (g >= NB) return;

  float4 P[NS];
#pragma unroll
  for (int s = 0; s < NS; ++s)
    P[s] = *(const float4*)(pooled + (((size_t)g << 3) + s) * 4);

  float h[4] = {0.f, 0.f, 0.f, 0.f};
  float c[4] = {0.f, 0.f, 0.f, 0.f};
#pragma unroll
  for (int s = 0; s < NS; ++s) {
    const float xv[4] = {P[s].x, P[s].y, P[s].z, P[s].w};
    float gates[16];
#pragma unroll
    for (int j = 0; j < 16; ++j) {
      float acc = b_ih[j] + b_hh[j];
#pragma unroll
      for (int qn = 0; qn < 4; ++qn) {
        acc = fmaf(xv[qn], w_ih[j * 4 + qn], acc);
        acc = fmaf(h[qn], w_hh[j * 4 + qn], acc);
      }
      gates[j] = acc;
    }
#pragma unroll
    for (int qn = 0; qn < 4; ++qn) {
      float ig = sigmoidf_(gates[qn]);
      float fg = sigmoidf_(gates[4 + qn]);
      float gg = tanhf_(gates[8 + qn]);
      float og = sigmoidf_(gates[12 + qn]);
      float cc = fmaf(fg, c[qn], ig * gg);
      c[qn] = cc;
      h[qn] = og * tanhf_(cc);
    }
  }
  float o0 = fc_b[0], o1 = fc_b[1];
#pragma unroll
  for (int qn = 0; qn < 4; ++qn) {
    o0 = fmaf(h[qn], fc_w[qn], o0);
    o1 = fmaf(h[qn], fc_w[4 + qn], o1);
  }
  out[(size_t)g * 2]     = o0;
  out[(size_t)g * 2 + 1] = o1;
}

// ---------------------------------------------------------------------------
extern "C" void kernel_launch(void* const* d_in, const int* in_sizes, int n_in,
                              void* d_out, int out_size, void* d_ws, size_t ws_size,
                              hipStream_t stream) {
  const float* x     = (const float*)d_in[0];
  const float* ew    = (const float*)d_in[3];
  const float* lin_w = (const float*)d_in[4];
  const float* lin_b = (const float*)d_in[5];
  const float* w_ih  = (const float*)d_in[6];
  const float* b_ih  = (const float*)d_in[7];
  const float* w_hh  = (const float*)d_in[8];
  const float* b_hh  = (const float*)d_in[9];
  const float* fc_w  = (const float*)d_in[10];
  const float* fc_b  = (const float*)d_in[11];
  float* out = (float*)d_out;

  // ws: Afrag [8][6][4][2][64][4] uint (384 KB), then pooled [1024][8][4] f32
  unsigned int* Afrag = (unsigned int*)d_ws;
  float* pooled = (float*)(Afrag + (size_t)NS * 12288);

  hipLaunchKernelGGL(build_frags_kernel, dim3(32), dim3(256), 0, stream,
                     ew, Afrag);
  // B launched 3x (idempotent, identical output) — ablation to isolate B's
  // marginal cost: dur(r19) - dur(r17) = 2*(B_warm + gap).
  hipLaunchKernelGGL(tag_pool_mfma_kernel, dim3(2048), dim3(256), 0, stream,
                     x, Afrag, lin_w, lin_b, pooled);
  hipLaunchKernelGGL(tag_pool_mfma_kernel, dim3(2048), dim3(256), 0, stream,
                     x, Afrag, lin_w, lin_b, pooled);
  hipLaunchKernelGGL(tag_pool_mfma_kernel, dim3(2048), dim3(256), 0, stream,
                     x, Afrag, lin_w, lin_b, pooled);
  hipLaunchKernelGGL(lstm_fc_kernel, dim3(NB / 64), dim3(64), 0, stream,
                     pooled, w_ih, b_ih, w_hh, b_hh, fc_w, fc_b, out);
}

// Round 20
// 42.149 us; speedup vs baseline: 1.5516x; 1.5516x over previous
//
#include <hip/hip_runtime.h>
#include <math.h>

#define NC    64
#define NT    128
#define NS    8
#define NFEAT 16
#define NE1   4032
#define NB    1024

typedef __attribute__((ext_vector_type(8))) short short8v;   // 8 bf16 carrier
typedef __attribute__((ext_vector_type(4))) float float4v;

__device__ __forceinline__ float sigmoidf_(float x) { return 1.f / (1.f + __expf(-x)); }
__device__ __forceinline__ float tanhf_(float x) {
  const float t = __expf(2.f * x);           // saturates correctly at +-inf
  return 1.f - 2.f / (t + 1.f);
}

__device__ __forceinline__ unsigned short bf16hi(float v) {
  return (unsigned short)(__float_as_uint(v) >> 16);
}
__device__ __forceinline__ float bf16hi_f(float v) {
  return __uint_as_float(__float_as_uint(v) & 0xffff0000u);
}

// ---------------------------------------------------------------------------
// Kernel A (verified r17): block = (s, nt). Analytic M build (closed-form
// edge order e(r,c) = r*63 + c - (c>r)), rows [nt*16,+16) of P2/P3 via row
// chains, pack A-operand MFMA fragments (hi/lo bf16) for K=192 [M|P2|P3] in
// mfma_f32_16x16x32_bf16 A-layout. Afrag[s][t6(6)][nt(4)][h(2)][64][4u].
// ---------------------------------------------------------------------------
__global__ __launch_bounds__(256) void build_frags_kernel(
    const float* __restrict__ ew, unsigned int* __restrict__ Afrag) {
  const int s  = blockIdx.x & 7;
  const int nt = blockIdx.x >> 3;
  const int t  = threadIdx.x;
  const int lane = t & 63;

  __shared__ float M[64][64];       // [out-node c][in-node r]
  __shared__ float P23[2][16][64];  // local rows of P2, P3
  __shared__ float dinv[64];
  __shared__ float dpart[4][64];

  const float* w = ew + s * NE1;

  {
    const int c  = t & 63;
    const int qr = t >> 6;
    float p = 0.f;
#pragma unroll
    for (int rr = 0; rr < 16; ++rr) {
      const int r = (qr << 4) | rr;
      if (r != c) p += w[r * 63 + c - (c > r ? 1 : 0)];
    }
    dpart[qr][c] = p;
  }
  __syncthreads();
  if (t < 64) {
    const float d = dpart[0][t] + dpart[1][t] + dpart[2][t] + dpart[3][t];
    dinv[t] = (d > 0.f) ? rsqrtf(d) : 0.f;
  }
  __syncthreads();

  for (int i = t; i < 4096; i += 256) {
    const int c = i >> 6, r = i & 63;
    M[c][r] = (r == c) ? 0.f
            : dinv[r] * w[r * 63 + c - (c > r ? 1 : 0)] * dinv[c];
  }
  __syncthreads();

  {
    const int rowl = ((t >> 6) << 2) | (lane >> 4);   // 0..15
    const int i    = (nt << 4) | rowl;
    const int jg4  = (lane & 15) << 2;
    float4v a2 = {0.f, 0.f, 0.f, 0.f};
#pragma unroll 8
    for (int m = 0; m < 64; ++m) {
      const float pim = M[i][m];
      const float4v mj = *(const float4v*)(&M[m][jg4]);
      a2 += pim * mj;
    }
    *(float4v*)(&P23[0][rowl][jg4]) = a2;
    float4v a3 = {0.f, 0.f, 0.f, 0.f};
#pragma unroll 8
    for (int m = 0; m < 64; ++m) {
      const float v2m = P23[0][rowl][m];              // same-wave DS ordering
      const float4v mj = *(const float4v*)(&M[m][jg4]);
      a3 += v2m * mj;
    }
    *(float4v*)(&P23[1][rowl][jg4]) = a3;
  }
  __syncthreads();

  for (int slot = t; slot < 768; slot += 256) {
    const int t6 = slot >> 7;              // 0..5
    const int h  = (slot >> 6) & 1;
    const int lf = slot & 63;
    const int rl = lf & 15;
    const int rg = (nt << 4) | rl;
    const int kb = (t6 << 5) | ((lf >> 4) << 3);
    uint4 u;
    unsigned int uu[4];
#pragma unroll
    for (int j = 0; j < 4; ++j) {
      unsigned short us[2];
#pragma unroll
      for (int e2 = 0; e2 < 2; ++e2) {
        const int k  = kb + (j << 1) + e2;
        const int kk = k >> 6;             // 0:M, 1:P2, 2:P3
        const int m  = k & 63;
        const float v = (kk == 0) ? M[rg][m] : P23[kk - 1][rl][m];
        us[e2] = h ? bf16hi(v - bf16hi_f(v)) : bf16hi(v);
      }
      uu[j] = (unsigned int)us[0] | ((unsigned int)us[1] << 16);
    }
    u.x = uu[0]; u.y = uu[1]; u.z = uu[2]; u.w = uu[3];
    unsigned int* dst = Afrag + ((((size_t)(s * 6 + t6) * 4 + nt) * 2 + h) << 8) + (lf << 2);
    *(uint4*)dst = u;
  }
}

// ---------------------------------------------------------------------------
// Kernel B (verified r17 exact, single launch): TAGConv via MFMA (K=192,
// acc init = V0) + ReLU + max-pool. s = blk>>8, quad q = blk&255 -> XCD q%8
// affinity. Load order: x -> Wl -> 12 A-frag b128. W via LDS uniform b128.
// ---------------------------------------------------------------------------
__global__ __launch_bounds__(256) void tag_pool_mfma_kernel(
    const float* __restrict__ x, const unsigned int* __restrict__ Afrag,
    const float* __restrict__ lin_w, const float* __restrict__ lin_b,
    float* __restrict__ pooled) {
  const int t    = threadIdx.x;
  const int lane = t & 63;
  const int w    = t >> 6;
  const int s    = blockIdx.x >> 8;                // step
  const int q    = blockIdx.x & 255;               // quad -> XCD q%8
  const int g0   = q << 2;
  const int col  = lane & 15;                      // B/C column = 4*g + o

  __shared__ __align__(16) float Wl[256];                   // [ko][f]
  __shared__ __align__(16) unsigned short zT[2][3][16][72]; // [h][kk][col][m pad72]
  __shared__ __align__(16) float V0f[16][68];               // [col][m pad68]
  __shared__ float pmax[4][16];

  // x loads FIRST (stage-1 needs them before anything else)
  float xf[16];
  {
    const float* xr = x + (((size_t)(g0 + w) << 6) + lane) * NT + s * NFEAT;
#pragma unroll
    for (int i = 0; i < 4; ++i)
      *(float4*)(&xf[i << 2]) = *(const float4*)(xr + (i << 2));
  }

  // W -> LDS (1KB, one coalesced load per thread)
  Wl[t] = lin_w[t];

  // A-fragment loads (consumed after the barrier; issued behind x)
  const unsigned int* Ab = Afrag + (size_t)s * 12288 + (lane << 2);
  short8v Ah0 = *(const short8v*)(Ab + (((0 * 4 + w) * 2 + 0) << 8));
  short8v Al0 = *(const short8v*)(Ab + (((0 * 4 + w) * 2 + 1) << 8));
  short8v Ah1 = *(const short8v*)(Ab + (((1 * 4 + w) * 2 + 0) << 8));
  short8v Al1 = *(const short8v*)(Ab + (((1 * 4 + w) * 2 + 1) << 8));
  short8v Ah2 = *(const short8v*)(Ab + (((2 * 4 + w) * 2 + 0) << 8));
  short8v Al2 = *(const short8v*)(Ab + (((2 * 4 + w) * 2 + 1) << 8));
  short8v Ah3 = *(const short8v*)(Ab + (((3 * 4 + w) * 2 + 0) << 8));
  short8v Al3 = *(const short8v*)(Ab + (((3 * 4 + w) * 2 + 1) << 8));
  short8v Ah4 = *(const short8v*)(Ab + (((4 * 4 + w) * 2 + 0) << 8));
  short8v Al4 = *(const short8v*)(Ab + (((4 * 4 + w) * 2 + 1) << 8));
  short8v Ah5 = *(const short8v*)(Ab + (((5 * 4 + w) * 2 + 0) << 8));
  short8v Al5 = *(const short8v*)(Ab + (((5 * 4 + w) * 2 + 1) << 8));

  __syncthreads();   // Wl visible to all waves

  // stage 1: wave w handles graph g0+w; lane = node. W via uniform LDS b128.
#pragma unroll
  for (int ko = 0; ko < 16; ++ko) {
    const float4 w0 = *(const float4*)(&Wl[(ko << 4)]);
    const float4 w1 = *(const float4*)(&Wl[(ko << 4) + 4]);
    const float4 w2 = *(const float4*)(&Wl[(ko << 4) + 8]);
    const float4 w3 = *(const float4*)(&Wl[(ko << 4) + 12]);
    float a = 0.f;
    a = fmaf(xf[0],  w0.x, a); a = fmaf(xf[1],  w0.y, a);
    a = fmaf(xf[2],  w0.z, a); a = fmaf(xf[3],  w0.w, a);
    a = fmaf(xf[4],  w1.x, a); a = fmaf(xf[5],  w1.y, a);
    a = fmaf(xf[6],  w1.z, a); a = fmaf(xf[7],  w1.w, a);
    a = fmaf(xf[8],  w2.x, a); a = fmaf(xf[9],  w2.y, a);
    a = fmaf(xf[10], w2.z, a); a = fmaf(xf[11], w2.w, a);
    a = fmaf(xf[12], w3.x, a); a = fmaf(xf[13], w3.y, a);
    a = fmaf(xf[14], w3.z, a); a = fmaf(xf[15], w3.w, a);
    const int kk = ko >> 2;
    const int cl = (w << 2) | (ko & 3);
    if (kk == 0) {
      V0f[cl][lane] = a;
    } else {
      zT[0][kk - 1][cl][lane] = bf16hi(a);
      zT[1][kk - 1][cl][lane] = bf16hi(a - bf16hi_f(a));
    }
  }
  __syncthreads();

  // acc init = V0[col][row] (identity term)
  float4v acc = *(const float4v*)(&V0f[col][(w << 4) | ((lane >> 4) << 2)]);

  // main loop: 6 k-steps of 32 over [M|P2|P3]; wave w owns A-row-tile nt=w.
#pragma unroll
  for (int t6 = 0; t6 < 6; ++t6) {
    const short8v Ah = (t6 == 0) ? Ah0 : (t6 == 1) ? Ah1 : (t6 == 2) ? Ah2
                     : (t6 == 3) ? Ah3 : (t6 == 4) ? Ah4 : Ah5;
    const short8v Al = (t6 == 0) ? Al0 : (t6 == 1) ? Al1 : (t6 == 2) ? Al2
                     : (t6 == 3) ? Al3 : (t6 == 4) ? Al4 : Al5;
    const int kk   = t6 >> 1;                       // 0:V1, 1:V2, 2:V3
    const int mloc = ((t6 & 1) << 5) | ((lane >> 4) << 3);
    const short8v Bh = *(const short8v*)(&zT[0][kk][col][mloc]);
    const short8v Bl = *(const short8v*)(&zT[1][kk][col][mloc]);
    acc = __builtin_amdgcn_mfma_f32_16x16x32_bf16(Ah, Bh, acc, 0, 0, 0);
    acc = __builtin_amdgcn_mfma_f32_16x16x32_bf16(Al, Bh, acc, 0, 0, 0);
    acc = __builtin_amdgcn_mfma_f32_16x16x32_bf16(Ah, Bl, acc, 0, 0, 0);
  }

  // epilogue: + bias, relu, max over tile's 16 rows, then block max
  const float bsA = lin_b[0] + lin_b[4] + lin_b[8]  + lin_b[12];
  const float bsB = lin_b[1] + lin_b[5] + lin_b[9]  + lin_b[13];
  const float bsC = lin_b[2] + lin_b[6] + lin_b[10] + lin_b[14];
  const float bsD = lin_b[3] + lin_b[7] + lin_b[11] + lin_b[15];
  const int oq = col & 3;
  const float bs = (oq == 0) ? bsA : (oq == 1) ? bsB : (oq == 2) ? bsC : bsD;

  float mx = 0.f;   // relu floor: outputs >= 0
#pragma unroll
  for (int r = 0; r < 4; ++r) mx = fmaxf(mx, fmaxf(acc[r] + bs, 0.f));
  mx = fmaxf(mx, __shfl_xor(mx, 16));
  mx = fmaxf(mx, __shfl_xor(mx, 32));
  if (lane < 16) pmax[w][lane] = mx;
  __syncthreads();

  if (t < 16) {
    const float m01 = fmaxf(pmax[0][t], pmax[1][t]);
    const float m23 = fmaxf(pmax[2][t], pmax[3][t]);
    pooled[((size_t)(g0 + (t >> 2)) * NS + s) * 4 + (t & 3)] = fmaxf(m01, m23);
  }
}

// ---------------------------------------------------------------------------
// Kernel C (verified r16): LSTM + FC, one thread per graph; pooled preloaded;
// fast exp forms.
// ---------------------------------------------------------------------------
__global__ __launch_bounds__(64) void lstm_fc_kernel(
    const float* __restrict__ pooled,
    const float* __restrict__ w_ih, const float* __restrict__ b_ih,
    const float* __restrict__ w_hh, const float* __restrict__ b_hh,
    const float* __restrict__ fc_w, const float* __restrict__ fc_b,
    float* __restrict__ out) {
  const int g = blockIdx.x * blockDim.x + threadIdx.x;
  if (g >= NB) return;

  float4 P[NS];
#pragma unroll
  for (int s = 0; s < NS; ++s)
    P[s] = *(const float4*)(pooled + (((size_t)g << 3) + s) * 4);

  float h[4] = {0.f, 0.f, 0.f, 0.f};
  float c[4] = {0.f, 0.f, 0.f, 0.f};
#pragma unroll
  for (int s = 0; s < NS; ++s) {
    const float xv[4] = {P[s].x, P[s].y, P[s].z, P[s].w};
    float gates[16];
#pragma unroll
    for (int j = 0; j < 16; ++j) {
      float acc = b_ih[j] + b_hh[j];
#pragma unroll
      for (int qn = 0; qn < 4; ++qn) {
        acc = fmaf(xv[qn], w_ih[j * 4 + qn], acc);
        acc = fmaf(h[qn], w_hh[j * 4 + qn], acc);
      }
      gates[j] = acc;
    }
#pragma unroll
    for (int qn = 0; qn < 4; ++qn) {
      float ig = sigmoidf_(gates[qn]);
      float fg = sigmoidf_(gates[4 + qn]);
      float gg = tanhf_(gates[8 + qn]);
      float og = sigmoidf_(gates[12 + qn]);
      float cc = fmaf(fg, c[qn], ig * gg);
      c[qn] = cc;
      h[qn] = og * tanhf_(cc);
    }
  }
  float o0 = fc_b[0], o1 = fc_b[1];
#pragma unroll
  for (int qn = 0; qn < 4; ++qn) {
    o0 = fmaf(h[qn], fc_w[qn], o0);
    o1 = fmaf(h[qn], fc_w[4 + qn], o1);
  }
  out[(size_t)g * 2]     = o0;
  out[(size_t)g * 2 + 1] = o1;
}

// ---------------------------------------------------------------------------
extern "C" void kernel_launch(void* const* d_in, const int* in_sizes, int n_in,
                              void* d_out, int out_size, void* d_ws, size_t ws_size,
                              hipStream_t stream) {
  const float* x     = (const float*)d_in[0];
  const float* ew    = (const float*)d_in[3];
  const float* lin_w = (const float*)d_in[4];
  const float* lin_b = (const float*)d_in[5];
  const float* w_ih  = (const float*)d_in[6];
  const float* b_ih  = (const float*)d_in[7];
  const float* w_hh  = (const float*)d_in[8];
  const float* b_hh  = (const float*)d_in[9];
  const float* fc_w  = (const float*)d_in[10];
  const float* fc_b  = (const float*)d_in[11];
  float* out = (float*)d_out;

  // ws: Afrag [8][6][4][2][64][4] uint (384 KB), then pooled [1024][8][4] f32
  unsigned int* Afrag = (unsigned int*)d_ws;
  float* pooled = (float*)(Afrag + (size_t)NS * 12288);

  hipLaunchKernelGGL(build_frags_kernel, dim3(32), dim3(256), 0, stream,
                     ew, Afrag);
  hipLaunchKernelGGL(tag_pool_mfma_kernel, dim3(2048), dim3(256), 0, stream,
                     x, Afrag, lin_w, lin_b, pooled);
  hipLaunchKernelGGL(lstm_fc_kernel, dim3(NB / 64), dim3(64), 0, stream,
                     pooled, w_ih, b_ih, w_hh, b_hh, fc_w, fc_b, out);
}